// Round 1
// baseline (610.985 us; speedup 1.0000x reference)
//
#include <hip/hip_runtime.h>

// Problem constants (from reference setup_inputs)
constexpr int N = 16, H = 768, W = 768;
constexpr int HW = H * W;
constexpr float EPS2 = 1.0e-6f;           // EPS^2, EPS = 0.001
constexpr float INV_W1 = 1.0f / (float)(W - 1);
constexpr float INV_H1 = 1.0f / (float)(H - 1);

// First warp, fully analytic: m1[b,:,yi,xi] = mask1 * bilinear(GridXY at (xi+fx, yi+fy))
// GridXY is analytic (x/(W-1), y/(H-1)) so no tensor read besides flo1 at (yi,xi).
__device__ __forceinline__ float2 warp_grid(const float* __restrict__ flo1, int b, int yi, int xi) {
    const float* base = flo1 + (size_t)b * 2 * HW;
    int off = yi * W + xi;
    float fx = base[off];
    float fy = base[HW + off];
    float gx = (float)xi + fx;
    float gy = (float)yi + fy;
    float x0 = floorf(gx), y0 = floorf(gy);
    float wx1 = gx - x0, wy1 = gy - y0;
    float wx0 = 1.0f - wx1, wy0 = 1.0f - wy1;
    float x1 = x0 + 1.0f, y1 = y0 + 1.0f;
    float vx0 = (x0 >= 0.0f && x0 <= (float)(W - 1)) ? 1.0f : 0.0f;
    float vx1 = (x1 >= 0.0f && x1 <= (float)(W - 1)) ? 1.0f : 0.0f;
    float vy0 = (y0 >= 0.0f && y0 <= (float)(H - 1)) ? 1.0f : 0.0f;
    float vy1 = (y1 >= 0.0f && y1 <= (float)(H - 1)) ? 1.0f : 0.0f;
    float w00 = wx0 * wy0 * vx0 * vy0;
    float w10 = wx1 * wy0 * vx1 * vy0;
    float w01 = wx0 * wy1 * vx0 * vy1;
    float w11 = wx1 * wy1 * vx1 * vy1;
    float msum = w00 + w10 + w01 + w11;
    // invalid corners have weight 0, so using raw x0/x1 (not clipped) is safe
    float gxv = ((w00 + w01) * x0 + (w10 + w11) * x1) * INV_W1;
    float gyv = ((w00 + w10) * y0 + (w01 + w11) * y1) * INV_H1;
    if (msum < 0.9999f) return make_float2(0.0f, 0.0f);
    return make_float2(gxv, gyv);
}

// One direction of the cycle loss at pixel (b,y,x):
// m2 = warp(warp(GridXY, flo1), flo2); returns sqrt(|Grid - m2|^2 + eps^2)
__device__ __forceinline__ float cycle_diff(const float* __restrict__ flo1,
                                            const float* __restrict__ flo2,
                                            int b, int y, int x) {
    const float* base2 = flo2 + (size_t)b * 2 * HW;
    int off = y * W + x;
    float fx = base2[off];
    float fy = base2[HW + off];
    float gx = (float)x + fx;
    float gy = (float)y + fy;
    float x0f = floorf(gx), y0f = floorf(gy);
    float wx1 = gx - x0f, wy1 = gy - y0f;
    float wx0 = 1.0f - wx1, wy0 = 1.0f - wy1;
    int x0 = (int)x0f, y0 = (int)y0f;
    bool vx0 = (x0f >= 0.0f) && (x0f <= (float)(W - 1));
    bool vx1 = (x0f >= -1.0f) && (x0f <= (float)(W - 2));
    bool vy0 = (y0f >= 0.0f) && (y0f <= (float)(H - 1));
    bool vy1 = (y0f >= -1.0f) && (y0f <= (float)(H - 2));

    float mx = 0.0f, my = 0.0f, msum = 0.0f;
    if (vy0) {
        if (vx0) { float w = wx0 * wy0; float2 m = warp_grid(flo1, b, y0, x0);
                   mx = fmaf(w, m.x, mx); my = fmaf(w, m.y, my); msum += w; }
        if (vx1) { float w = wx1 * wy0; float2 m = warp_grid(flo1, b, y0, x0 + 1);
                   mx = fmaf(w, m.x, mx); my = fmaf(w, m.y, my); msum += w; }
    }
    if (vy1) {
        if (vx0) { float w = wx0 * wy1; float2 m = warp_grid(flo1, b, y0 + 1, x0);
                   mx = fmaf(w, m.x, mx); my = fmaf(w, m.y, my); msum += w; }
        if (vx1) { float w = wx1 * wy1; float2 m = warp_grid(flo1, b, y0 + 1, x0 + 1);
                   mx = fmaf(w, m.x, mx); my = fmaf(w, m.y, my); msum += w; }
    }
    if (msum < 0.9999f) { mx = 0.0f; my = 0.0f; }
    float Gx = (float)x * INV_W1;
    float Gy = (float)y * INV_H1;
    float dx = Gx - mx, dy = Gy - my;
    return sqrtf(fmaf(dx, dx, fmaf(dy, dy, EPS2)));
}

__global__ __launch_bounds__(256)
void cycle_loss_kernel(const float* __restrict__ A,   // UV_AtoB
                       const float* __restrict__ B,   // UV_BtoA
                       float* __restrict__ out) {
    int idx = blockIdx.x * blockDim.x + threadIdx.x;   // over N*H*W, exact fit
    int x = idx % W;
    int t = idx / W;
    int y = t % H;
    int b = t / H;

    float s = cycle_diff(A, B, b, y, x)    // ABA: flo1 = A, flo2 = B
            + cycle_diff(B, A, b, y, x);   // BAB: flo1 = B, flo2 = A

    // wave(64) shuffle reduce -> LDS -> one atomic per block
    #pragma unroll
    for (int o = 32; o > 0; o >>= 1) s += __shfl_down(s, o, 64);
    __shared__ float wsum[4];
    int lane = threadIdx.x & 63, wv = threadIdx.x >> 6;
    if (lane == 0) wsum[wv] = s;
    __syncthreads();
    if (threadIdx.x == 0) {
        float tsum = wsum[0] + wsum[1] + wsum[2] + wsum[3];
        atomicAdd(out, tsum * (1.0f / ((float)N * (float)H * (float)W)));
    }
}

extern "C" void kernel_launch(void* const* d_in, const int* in_sizes, int n_in,
                              void* d_out, int out_size, void* d_ws, size_t ws_size,
                              hipStream_t stream) {
    const float* A = (const float*)d_in[0];   // UV_AtoB [16,2,768,768]
    const float* B = (const float*)d_in[1];   // UV_BtoA [16,2,768,768]
    float* out = (float*)d_out;               // scalar fp32

    // d_out is poisoned 0xAA before every timed launch; zero it (graph-capturable memset node)
    hipMemsetAsync(out, 0, sizeof(float), stream);

    int total = N * H * W;                    // 9,437,184 = 36864 * 256
    cycle_loss_kernel<<<total / 256, 256, 0, stream>>>(A, B, out);
}

// Round 2
// 595.425 us; speedup vs baseline: 1.0261x; 1.0261x over previous
//
#include <hip/hip_runtime.h>

// Problem constants (from reference setup_inputs)
constexpr int N = 16, H = 768, W = 768;
constexpr int HW = H * W;
constexpr float EPS2 = 1.0e-6f;           // EPS^2, EPS = 0.001
constexpr float INV_W1 = 1.0f / (float)(W - 1);
constexpr float INV_H1 = 1.0f / (float)(H - 1);

// Analytic first warp: m1 at integer pixel (xi,yi) given its flow (fx,fy).
// GridXY is analytic (x/(W-1), y/(H-1)) so this is pure VALU — no memory.
// Branch-free: invalid corner weights zeroed, mask binarization via select.
__device__ __forceinline__ float2 warp_grid_val(float fx, float fy, int xi, int yi) {
    float gx = (float)xi + fx;
    float gy = (float)yi + fy;
    float x0 = floorf(gx), y0 = floorf(gy);
    float wx1 = gx - x0, wy1 = gy - y0;
    float wx0 = 1.0f - wx1, wy0 = 1.0f - wy1;
    float x1 = x0 + 1.0f, y1 = y0 + 1.0f;
    float vx0 = (x0 >= 0.0f && x0 <= (float)(W - 1)) ? 1.0f : 0.0f;
    float vx1 = (x1 >= 0.0f && x1 <= (float)(W - 1)) ? 1.0f : 0.0f;
    float vy0 = (y0 >= 0.0f && y0 <= (float)(H - 1)) ? 1.0f : 0.0f;
    float vy1 = (y1 >= 0.0f && y1 <= (float)(H - 1)) ? 1.0f : 0.0f;
    float w00 = wx0 * wy0 * vx0 * vy0;
    float w10 = wx1 * wy0 * vx1 * vy0;
    float w01 = wx0 * wy1 * vx0 * vy1;
    float w11 = wx1 * wy1 * vx1 * vy1;
    float msum = w00 + w10 + w01 + w11;
    // invalid corners have weight 0, so raw (unclipped) x0/x1 is safe
    float gxv = ((w00 + w01) * x0 + (w10 + w11) * x1) * INV_W1;
    float gyv = ((w00 + w10) * y0 + (w01 + w11) * y1) * INV_H1;
    float keep = (msum >= 0.9999f) ? 1.0f : 0.0f;
    return make_float2(gxv * keep, gyv * keep);
}

// One direction: m2 = warp(warp(GridXY, f1), f2) at pixel (x,y), where
// (fx,fy) = f2's flow at (x,y) (already loaded, coalesced, by the caller).
// Branch-free: corner coords clamped, invalid weights zeroed, so all 8
// gathers from f1 issue unconditionally (max MLP, no exec-mask serialization).
__device__ __forceinline__ float cycle_dir(const float* __restrict__ f1,
                                           float fx, float fy, int x, int y) {
    float gx = (float)x + fx;
    float gy = (float)y + fy;
    float x0f = floorf(gx), y0f = floorf(gy);
    float wx1 = gx - x0f, wy1 = gy - y0f;
    float wx0 = 1.0f - wx1, wy0 = 1.0f - wy1;
    float x1f = x0f + 1.0f, y1f = y0f + 1.0f;
    float vx0 = (x0f >= 0.0f && x0f <= (float)(W - 1)) ? 1.0f : 0.0f;
    float vx1 = (x1f >= 0.0f && x1f <= (float)(W - 1)) ? 1.0f : 0.0f;
    float vy0 = (y0f >= 0.0f && y0f <= (float)(H - 1)) ? 1.0f : 0.0f;
    float vy1 = (y1f >= 0.0f && y1f <= (float)(H - 1)) ? 1.0f : 0.0f;
    // clamp on the float side (safe int cast even for wild flow values)
    float x0c = fminf(fmaxf(x0f, 0.0f), (float)(W - 1));
    float x1c = fminf(fmaxf(x1f, 0.0f), (float)(W - 1));
    float y0c = fminf(fmaxf(y0f, 0.0f), (float)(H - 1));
    float y1c = fminf(fmaxf(y1f, 0.0f), (float)(H - 1));
    int xi0 = (int)x0c, xi1 = (int)x1c, yi0 = (int)y0c, yi1 = (int)y1c;
    int o00 = yi0 * W + xi0, o01 = yi0 * W + xi1;
    int o10 = yi1 * W + xi0, o11 = yi1 * W + xi1;

    // 8 unconditional gathers — all issue before the first use
    float a00x = f1[o00],      a00y = f1[HW + o00];
    float a01x = f1[o01],      a01y = f1[HW + o01];
    float a10x = f1[o10],      a10y = f1[HW + o10];
    float a11x = f1[o11],      a11y = f1[HW + o11];

    float w00 = wx0 * wy0 * vx0 * vy0;
    float w10 = wx1 * wy0 * vx1 * vy0;
    float w01 = wx0 * wy1 * vx0 * vy1;
    float w11 = wx1 * wy1 * vx1 * vy1;
    float msum = w00 + w10 + w01 + w11;

    float2 m00 = warp_grid_val(a00x, a00y, xi0, yi0);
    float2 m01 = warp_grid_val(a01x, a01y, xi1, yi0);
    float2 m10 = warp_grid_val(a10x, a10y, xi0, yi1);
    float2 m11 = warp_grid_val(a11x, a11y, xi1, yi1);

    float mx = w00 * m00.x + w10 * m01.x + w01 * m10.x + w11 * m11.x;
    float my = w00 * m00.y + w10 * m01.y + w01 * m10.y + w11 * m11.y;
    float keep = (msum >= 0.9999f) ? 1.0f : 0.0f;
    mx *= keep; my *= keep;

    float Gx = (float)x * INV_W1;
    float Gy = (float)y * INV_H1;
    float dx = Gx - mx, dy = Gy - my;
    return sqrtf(fmaf(dx, dx, fmaf(dy, dy, EPS2)));
}

// Block = 64 (x) × 4 (y) tile: gather footprint ~8 rows × 72 cols × 2ch × 2
// tensors ≈ 9 KB → L1-resident within-block reuse; x-adjacent consecutive
// blocks share halo rows for L2 reuse.
__global__ __launch_bounds__(256)
void cycle_loss_kernel(const float* __restrict__ A,   // UV_AtoB
                       const float* __restrict__ B,   // UV_BtoA
                       float* __restrict__ out) {
    int lane = threadIdx.x & 63;
    int wv   = threadIdx.x >> 6;
    int x = blockIdx.x * 64 + lane;
    int y = blockIdx.y * 4 + wv;
    int b = blockIdx.z;

    size_t base = (size_t)b * 2 * HW;
    int off = y * W + x;
    // 4 coalesced center loads (both tensors' flows at this pixel), issued together
    float aX = A[base + off], aY = A[base + HW + off];
    float bX = B[base + off], bY = B[base + HW + off];

    // ABA: flo1 = A (gathered), flo2 = B (outer flow at center)
    // BAB: flo1 = B (gathered), flo2 = A — both inlined, 16 gathers in flight
    float s = cycle_dir(A + base, bX, bY, x, y)
            + cycle_dir(B + base, aX, aY, x, y);

    // wave(64) shuffle reduce -> LDS -> one atomic per block
    #pragma unroll
    for (int o = 32; o > 0; o >>= 1) s += __shfl_down(s, o, 64);
    __shared__ float wsum[4];
    if (lane == 0) wsum[wv] = s;
    __syncthreads();
    if (threadIdx.x == 0) {
        float tsum = wsum[0] + wsum[1] + wsum[2] + wsum[3];
        atomicAdd(out, tsum * (1.0f / ((float)N * (float)H * (float)W)));
    }
}

extern "C" void kernel_launch(void* const* d_in, const int* in_sizes, int n_in,
                              void* d_out, int out_size, void* d_ws, size_t ws_size,
                              hipStream_t stream) {
    const float* A = (const float*)d_in[0];   // UV_AtoB [16,2,768,768]
    const float* B = (const float*)d_in[1];   // UV_BtoA [16,2,768,768]
    float* out = (float*)d_out;               // scalar fp32

    hipMemsetAsync(out, 0, sizeof(float), stream);

    dim3 grid(W / 64, H / 4, N);              // (12, 192, 16) = 36864 blocks
    cycle_loss_kernel<<<grid, 256, 0, stream>>>(A, B, out);
}

// Round 3
// 260.035 us; speedup vs baseline: 2.3496x; 2.2898x over previous
//
#include <hip/hip_runtime.h>

// Problem constants (from reference setup_inputs)
constexpr int N = 16, H = 768, W = 768;
constexpr int HW = H * W;
constexpr float EPS2 = 1.0e-6f;           // EPS^2, EPS = 0.001
constexpr float INV_W1 = 1.0f / (float)(W - 1);
constexpr float INV_H1 = 1.0f / (float)(H - 1);
constexpr float WM1 = (float)(W - 1);
constexpr float HM1 = (float)(H - 1);
constexpr int PX = 4;                      // pixels (rows) per thread

// 8-byte vector with 4-byte alignment promise: lets the compiler emit
// global_load_dwordx2 at dword-aligned (not 8B-aligned) addresses.
typedef float float2a __attribute__((ext_vector_type(2), aligned(4)));

// Per-pixel, per-direction metadata kept across the load phase.
struct DirMeta { float gx, gy; int o0, o1; };

__device__ __forceinline__ void dir_meta(float fx, float fy, int x, int y, DirMeta& m) {
    m.gx = (float)x + fx;
    m.gy = (float)y + fy;
    float x0f = floorf(m.gx);
    float y0f = floorf(m.gy);
    // pair base column: covers {xb, xb+1} ⊇ {clamp(x0), clamp(x0+1)} always
    float xbf = fminf(fmaxf(x0f, 0.0f), (float)(W - 2));
    float y0c = fminf(fmaxf(y0f, 0.0f), HM1);
    float y1c = fminf(fmaxf(y0f + 1.0f, 0.0f), HM1);
    int xbi = (int)xbf;
    m.o0 = (int)y0c * W + xbi;     // row y0, cols {xb, xb+1}
    m.o1 = (int)y1c * W + xbi;     // row y1
}

// Analytic inner warp: m1 at integer corner (xi,yi) with its flow (fx,fy).
// Exact algebraic refactor of the reference bilinear+mask:
//   gxv = sy*(sx*x0 + bx), gyv = sx*(sy*y0 + by), msum = sx*sy
__device__ __forceinline__ float2 wg(float fx, float fy, float xi, float yi) {
    float gx = xi + fx, gy = yi + fy;
    float x0 = floorf(gx), y0 = floorf(gy);
    float wx1 = gx - x0, wx0 = 1.0f - wx1;
    float wy1 = gy - y0, wy0 = 1.0f - wy1;
    float vx0 = (x0 >= 0.0f  && x0 <= WM1)        ? 1.0f : 0.0f;
    float vx1 = (x0 >= -1.0f && x0 <= WM1 - 1.0f) ? 1.0f : 0.0f;
    float vy0 = (y0 >= 0.0f  && y0 <= HM1)        ? 1.0f : 0.0f;
    float vy1 = (y0 >= -1.0f && y0 <= HM1 - 1.0f) ? 1.0f : 0.0f;
    float ax = wx0 * vx0, bx = wx1 * vx1, sx = ax + bx;
    float ay = wy0 * vy0, by = wy1 * vy1, sy = ay + by;
    float ms = sx * sy;
    float kx = (ms >= 0.9999f) ? INV_W1 : 0.0f;
    float ky = (ms >= 0.9999f) ? INV_H1 : 0.0f;
    float2 r;
    r.x = fmaf(sx, x0, bx) * sy * kx;
    r.y = fmaf(sy, y0, by) * sx * ky;
    return r;
}

// Evaluate one direction at one pixel from the 4 preloaded pairs.
// r0x/r0y = row-y0 pairs (ch x / ch y), r1x/r1y = row-y1 pairs.
__device__ __forceinline__ float dir_eval(const DirMeta& m,
                                          float2a r0x, float2a r0y,
                                          float2a r1x, float2a r1y,
                                          int x, int y) {
    float x0f = floorf(m.gx), y0f = floorf(m.gy);
    float wx1 = m.gx - x0f, wx0 = 1.0f - wx1;
    float wy1 = m.gy - y0f, wy0 = 1.0f - wy1;
    float x1f = x0f + 1.0f, y1f = y0f + 1.0f;
    float vx0 = (x0f >= 0.0f && x0f <= WM1) ? 1.0f : 0.0f;
    float vx1 = (x1f >= 0.0f && x1f <= WM1) ? 1.0f : 0.0f;
    float vy0 = (y0f >= 0.0f && y0f <= HM1) ? 1.0f : 0.0f;
    float vy1 = (y1f >= 0.0f && y1f <= HM1) ? 1.0f : 0.0f;
    float axw = wx0 * vx0, bxw = wx1 * vx1;
    float ayw = wy0 * vy0, byw = wy1 * vy1;
    float sxw = axw + bxw, syw = ayw + byw;
    float msum = sxw * syw;

    // pair-index selects: base xb = clamp(x0,0,W-2); col xi0 is .y only when
    // x0 >= W-1; col xi1 is .y exactly when x0 >= 0 (else both clamp to 0).
    bool selA = (x0f >= WM1);
    bool selB = (x0f >= 0.0f);
    float fx00 = selA ? r0x.y : r0x.x;   // gathered flow ch-x at (y0, xi0)
    float fx01 = selB ? r0x.y : r0x.x;   // (y0, xi1)
    float fy00 = selA ? r0y.y : r0y.x;
    float fy01 = selB ? r0y.y : r0y.x;
    float fx10 = selA ? r1x.y : r1x.x;
    float fx11 = selB ? r1x.y : r1x.x;
    float fy10 = selA ? r1y.y : r1y.x;
    float fy11 = selB ? r1y.y : r1y.x;

    // clamped corner coords (valid corners are unmoved; invalid have weight 0)
    float x0c = fminf(fmaxf(x0f, 0.0f), WM1);
    float x1c = fminf(fmaxf(x1f, 0.0f), WM1);
    float y0c = fminf(fmaxf(y0f, 0.0f), HM1);
    float y1c = fminf(fmaxf(y1f, 0.0f), HM1);

    float2 m00 = wg(fx00, fy00, x0c, y0c);
    float2 m01 = wg(fx01, fy01, x1c, y0c);
    float2 m10 = wg(fx10, fy10, x0c, y1c);
    float2 m11 = wg(fx11, fy11, x1c, y1c);

    float w00 = axw * ayw, w10 = bxw * ayw, w01 = axw * byw, w11 = bxw * byw;
    float mx = w00 * m00.x + w10 * m01.x + w01 * m10.x + w11 * m11.x;
    float my = w00 * m00.y + w10 * m01.y + w01 * m10.y + w11 * m11.y;
    float keep = (msum >= 0.9999f) ? 1.0f : 0.0f;
    mx *= keep; my *= keep;

    float dx = (float)x * INV_W1 - mx;
    float dy = (float)y * INV_H1 - my;
    return sqrtf(fmaf(dx, dx, fmaf(dy, dy, EPS2)));
}

// Block = 64 lanes × 4 waves, each thread does PX=4 consecutive rows
// → block tile 64 cols × 16 rows. All loads batched per phase for MLP.
__global__ __launch_bounds__(256)
void cycle_loss_kernel(const float* __restrict__ A,   // UV_AtoB
                       const float* __restrict__ B,   // UV_BtoA
                       float* __restrict__ out) {
    int lane = threadIdx.x & 63;
    int wv   = threadIdx.x >> 6;
    int x  = blockIdx.x * 64 + lane;
    int yb = (blockIdx.y * 4 + wv) * PX;
    int b  = blockIdx.z;
    const float* Ab = A + (size_t)b * 2 * HW;
    const float* Bb = B + (size_t)b * 2 * HW;

    // phase 0: 16 coalesced center loads (outer flows for both directions)
    float aX[PX], aY[PX], bX[PX], bY[PX];
    #pragma unroll
    for (int p = 0; p < PX; ++p) {
        int off = (yb + p) * W + x;
        aX[p] = Ab[off]; aY[p] = Ab[HW + off];
        bX[p] = Bb[off]; bY[p] = Bb[HW + off];
    }

    // phase 1: gather metadata. ABA: outer flow = B, gather tensor = A. BAB: swapped.
    DirMeta m1[PX], m2[PX];
    #pragma unroll
    for (int p = 0; p < PX; ++p) {
        dir_meta(bX[p], bY[p], x, yb + p, m1[p]);
        dir_meta(aX[p], aY[p], x, yb + p, m2[p]);
    }

    // phase 2: 32 independent paired gathers (dwordx2), all issued before use
    float2a g1[PX][4], g2[PX][4];
    #pragma unroll
    for (int p = 0; p < PX; ++p) {
        g1[p][0] = *(const float2a*)(Ab + m1[p].o0);
        g1[p][1] = *(const float2a*)(Ab + HW + m1[p].o0);
        g1[p][2] = *(const float2a*)(Ab + m1[p].o1);
        g1[p][3] = *(const float2a*)(Ab + HW + m1[p].o1);
        g2[p][0] = *(const float2a*)(Bb + m2[p].o0);
        g2[p][1] = *(const float2a*)(Bb + HW + m2[p].o0);
        g2[p][2] = *(const float2a*)(Bb + m2[p].o1);
        g2[p][3] = *(const float2a*)(Bb + HW + m2[p].o1);
    }

    // phase 3: pure VALU
    float s = 0.0f;
    #pragma unroll
    for (int p = 0; p < PX; ++p) {
        s += dir_eval(m1[p], g1[p][0], g1[p][1], g1[p][2], g1[p][3], x, yb + p);
        s += dir_eval(m2[p], g2[p][0], g2[p][1], g2[p][2], g2[p][3], x, yb + p);
    }

    // wave(64) shuffle reduce -> LDS -> one atomic per block
    #pragma unroll
    for (int o = 32; o > 0; o >>= 1) s += __shfl_down(s, o, 64);
    __shared__ float wsum[4];
    if (lane == 0) wsum[wv] = s;
    __syncthreads();
    if (threadIdx.x == 0) {
        float tsum = wsum[0] + wsum[1] + wsum[2] + wsum[3];
        atomicAdd(out, tsum * (1.0f / ((float)N * (float)H * (float)W)));
    }
}

extern "C" void kernel_launch(void* const* d_in, const int* in_sizes, int n_in,
                              void* d_out, int out_size, void* d_ws, size_t ws_size,
                              hipStream_t stream) {
    const float* A = (const float*)d_in[0];   // UV_AtoB [16,2,768,768]
    const float* B = (const float*)d_in[1];   // UV_BtoA [16,2,768,768]
    float* out = (float*)d_out;               // scalar fp32

    hipMemsetAsync(out, 0, sizeof(float), stream);

    dim3 grid(W / 64, H / (4 * PX), N);       // (12, 48, 16) = 9216 blocks
    cycle_loss_kernel<<<grid, 256, 0, stream>>>(A, B, out);
}

// Round 4
// 254.328 us; speedup vs baseline: 2.4024x; 1.0224x over previous
//
#include <hip/hip_runtime.h>

// Problem constants (from reference setup_inputs)
constexpr int N = 16, H = 768, W = 768;
constexpr int HW = H * W;
constexpr float EPS2 = 1.0e-6f;           // EPS^2, EPS = 0.001
constexpr float INV_W1 = 1.0f / (float)(W - 1);
constexpr float INV_H1 = 1.0f / (float)(H - 1);
constexpr float WM1 = (float)(W - 1);
constexpr float HM1 = (float)(H - 1);
constexpr float WM2 = (float)(W - 2);
constexpr float HM2 = (float)(H - 2);
constexpr int PX = 4;                      // pixels (rows) per thread

// 8-byte vector with 4-byte alignment promise (dword-aligned dwordx2 loads)
typedef float float2a __attribute__((ext_vector_type(2), aligned(4)));

struct DirMeta { float gx, gy; int o0, o1; };

__device__ __forceinline__ void dir_meta(float fx, float fy, int x, int y, DirMeta& m) {
    m.gx = (float)x + fx;
    m.gy = (float)y + fy;
    float x0f = floorf(m.gx);
    float y0f = floorf(m.gy);
    // pair base column: covers {xb, xb+1} ⊇ {clamp(x0), clamp(x0+1)} always
    float xbf = fminf(fmaxf(x0f, 0.0f), WM2);
    float y0c = fminf(fmaxf(y0f, 0.0f), HM1);
    float y1c = fminf(fmaxf(y0f + 1.0f, 0.0f), HM1);
    int xbi = (int)xbf;
    m.o0 = (int)y0c * W + xbi;     // row y0, cols {xb, xb+1}
    m.o1 = (int)y1c * W + xbi;     // row y1
}

// ---------- fast path ----------------------------------------------------
// Eligible iff outer floor in [0,W-2]x[0,H-2] (so the gathered pair IS
// (x0,x0+1) unclamped) and all 4 inner sample coords are in [0,W-1]x[0,H-1]
// (then every mask is exactly 1 and bilinear-of-linear-grid is the identity).
__device__ __forceinline__ bool fast_ok(const DirMeta& m,
                                        float2a g0, float2a g1, float2a g2, float2a g3) {
    float x0f = floorf(m.gx), y0f = floorf(m.gy);
    bool ok = (x0f >= 0.0f) & (x0f <= WM2) & (y0f >= 0.0f) & (y0f <= HM2);
    float x1f = x0f + 1.0f, y1f = y0f + 1.0f;
    float gx00 = x0f + g0.x, gx01 = x1f + g0.y;
    float gx10 = x0f + g2.x, gx11 = x1f + g2.y;
    float gy00 = y0f + g1.x, gy01 = y0f + g1.y;
    float gy10 = y1f + g3.x, gy11 = y1f + g3.y;
    float xlo = fminf(fminf(gx00, gx01), fminf(gx10, gx11));
    float xhi = fmaxf(fmaxf(gx00, gx01), fmaxf(gx10, gx11));
    float ylo = fminf(fminf(gy00, gy01), fminf(gy10, gy11));
    float yhi = fmaxf(fmaxf(gy00, gy01), fmaxf(gy10, gy11));
    ok &= (xlo >= 0.0f) & (xhi <= WM1) & (ylo >= 0.0f) & (yhi <= HM1);
    return ok;
}

// All-valid residual: masks are 1 and the inner warp is the identity on the
// grid, so  diff = sqrt(((fxc + bilerp fx)/ (W-1))^2 + ((fyc + bilerp fy)/(H-1))^2 + eps^2)
__device__ __forceinline__ float fast_eval(const DirMeta& m,
                                           float2a g0, float2a g1, float2a g2, float2a g3,
                                           float fxc, float fyc) {
    float x0f = floorf(m.gx), y0f = floorf(m.gy);   // CSE'd with fast_ok
    float wx1 = m.gx - x0f, wy1 = m.gy - y0f;
    float ftx = fmaf(wx1, g0.y - g0.x, g0.x);
    float fbx = fmaf(wx1, g2.y - g2.x, g2.x);
    float fxv = fmaf(wy1, fbx - ftx, ftx);
    float fty = fmaf(wx1, g1.y - g1.x, g1.x);
    float fby = fmaf(wx1, g3.y - g3.x, g3.x);
    float fyv = fmaf(wy1, fby - fty, fty);
    float a = (fxc + fxv) * INV_W1;
    float b = (fyc + fyv) * INV_H1;
    return sqrtf(fmaf(a, a, fmaf(b, b, EPS2)));
}

// ---------- general (border / wild-flow) path -----------------------------
__device__ __forceinline__ float2 wg(float fx, float fy, float xi, float yi) {
    float gx = xi + fx, gy = yi + fy;
    float x0 = floorf(gx), y0 = floorf(gy);
    float wx1 = gx - x0, wx0 = 1.0f - wx1;
    float wy1 = gy - y0, wy0 = 1.0f - wy1;
    float vx0 = (x0 >= 0.0f  && x0 <= WM1)        ? 1.0f : 0.0f;
    float vx1 = (x0 >= -1.0f && x0 <= WM1 - 1.0f) ? 1.0f : 0.0f;
    float vy0 = (y0 >= 0.0f  && y0 <= HM1)        ? 1.0f : 0.0f;
    float vy1 = (y0 >= -1.0f && y0 <= HM1 - 1.0f) ? 1.0f : 0.0f;
    float ax = wx0 * vx0, bx = wx1 * vx1, sx = ax + bx;
    float ay = wy0 * vy0, by = wy1 * vy1, sy = ay + by;
    float ms = sx * sy;
    float kx = (ms >= 0.9999f) ? INV_W1 : 0.0f;
    float ky = (ms >= 0.9999f) ? INV_H1 : 0.0f;
    float2 r;
    r.x = fmaf(sx, x0, bx) * sy * kx;
    r.y = fmaf(sy, y0, by) * sx * ky;
    return r;
}

__device__ __forceinline__ float dir_eval(const DirMeta& m,
                                          float2a r0x, float2a r0y,
                                          float2a r1x, float2a r1y,
                                          int x, int y) {
    float x0f = floorf(m.gx), y0f = floorf(m.gy);
    float wx1 = m.gx - x0f, wx0 = 1.0f - wx1;
    float wy1 = m.gy - y0f, wy0 = 1.0f - wy1;
    float x1f = x0f + 1.0f, y1f = y0f + 1.0f;
    float vx0 = (x0f >= 0.0f && x0f <= WM1) ? 1.0f : 0.0f;
    float vx1 = (x1f >= 0.0f && x1f <= WM1) ? 1.0f : 0.0f;
    float vy0 = (y0f >= 0.0f && y0f <= HM1) ? 1.0f : 0.0f;
    float vy1 = (y1f >= 0.0f && y1f <= HM1) ? 1.0f : 0.0f;
    float axw = wx0 * vx0, bxw = wx1 * vx1;
    float ayw = wy0 * vy0, byw = wy1 * vy1;
    float sxw = axw + bxw, syw = ayw + byw;
    float msum = sxw * syw;

    // pair-index selects: base xb = clamp(x0,0,W-2)
    bool selA = (x0f >= WM1);
    bool selB = (x0f >= 0.0f);
    float fx00 = selA ? r0x.y : r0x.x;
    float fx01 = selB ? r0x.y : r0x.x;
    float fy00 = selA ? r0y.y : r0y.x;
    float fy01 = selB ? r0y.y : r0y.x;
    float fx10 = selA ? r1x.y : r1x.x;
    float fx11 = selB ? r1x.y : r1x.x;
    float fy10 = selA ? r1y.y : r1y.x;
    float fy11 = selB ? r1y.y : r1y.x;

    float x0c = fminf(fmaxf(x0f, 0.0f), WM1);
    float x1c = fminf(fmaxf(x1f, 0.0f), WM1);
    float y0c = fminf(fmaxf(y0f, 0.0f), HM1);
    float y1c = fminf(fmaxf(y1f, 0.0f), HM1);

    float2 m00 = wg(fx00, fy00, x0c, y0c);
    float2 m01 = wg(fx01, fy01, x1c, y0c);
    float2 m10 = wg(fx10, fy10, x0c, y1c);
    float2 m11 = wg(fx11, fy11, x1c, y1c);

    float w00 = axw * ayw, w10 = bxw * ayw, w01 = axw * byw, w11 = bxw * byw;
    float mx = w00 * m00.x + w10 * m01.x + w01 * m10.x + w11 * m11.x;
    float my = w00 * m00.y + w10 * m01.y + w01 * m10.y + w11 * m11.y;
    float keep = (msum >= 0.9999f) ? 1.0f : 0.0f;
    mx *= keep; my *= keep;

    float dx = (float)x * INV_W1 - mx;
    float dy = (float)y * INV_H1 - my;
    return sqrtf(fmaf(dx, dx, fmaf(dy, dy, EPS2)));
}

// Block = 64 lanes × 4 waves, each thread does PX=4 consecutive rows.
__global__ __launch_bounds__(256)
void cycle_loss_kernel(const float* __restrict__ A,   // UV_AtoB
                       const float* __restrict__ B,   // UV_BtoA
                       float* __restrict__ out) {
    int lane = threadIdx.x & 63;
    int wv   = threadIdx.x >> 6;
    int x  = blockIdx.x * 64 + lane;
    int yb = (blockIdx.y * 4 + wv) * PX;
    int b  = blockIdx.z;
    const float* Ab = A + (size_t)b * 2 * HW;
    const float* Bb = B + (size_t)b * 2 * HW;

    // phase 0: 16 coalesced center loads
    float aX[PX], aY[PX], bX[PX], bY[PX];
    #pragma unroll
    for (int p = 0; p < PX; ++p) {
        int off = (yb + p) * W + x;
        aX[p] = Ab[off]; aY[p] = Ab[HW + off];
        bX[p] = Bb[off]; bY[p] = Bb[HW + off];
    }

    // phase 1: gather metadata. ABA: outer flow = B, gather A. BAB: swapped.
    DirMeta m1[PX], m2[PX];
    #pragma unroll
    for (int p = 0; p < PX; ++p) {
        dir_meta(bX[p], bY[p], x, yb + p, m1[p]);
        dir_meta(aX[p], aY[p], x, yb + p, m2[p]);
    }

    // phase 2: 32 independent paired gathers, all issued before first use
    float2a g1[PX][4], g2[PX][4];
    #pragma unroll
    for (int p = 0; p < PX; ++p) {
        g1[p][0] = *(const float2a*)(Ab + m1[p].o0);
        g1[p][1] = *(const float2a*)(Ab + HW + m1[p].o0);
        g1[p][2] = *(const float2a*)(Ab + m1[p].o1);
        g1[p][3] = *(const float2a*)(Ab + HW + m1[p].o1);
        g2[p][0] = *(const float2a*)(Bb + m2[p].o0);
        g2[p][1] = *(const float2a*)(Bb + HW + m2[p].o0);
        g2[p][2] = *(const float2a*)(Bb + m2[p].o1);
        g2[p][3] = *(const float2a*)(Bb + HW + m2[p].o1);
    }

    // phase 3: compute. Wave-uniform fast/slow branch per pixel.
    float s = 0.0f;
    #pragma unroll
    for (int p = 0; p < PX; ++p) {
        int y = yb + p;
        bool ok = fast_ok(m1[p], g1[p][0], g1[p][1], g1[p][2], g1[p][3])
                & fast_ok(m2[p], g2[p][0], g2[p][1], g2[p][2], g2[p][3]);
        if (__all(ok)) {
            s += fast_eval(m1[p], g1[p][0], g1[p][1], g1[p][2], g1[p][3], bX[p], bY[p]);
            s += fast_eval(m2[p], g2[p][0], g2[p][1], g2[p][2], g2[p][3], aX[p], aY[p]);
        } else {
            s += dir_eval(m1[p], g1[p][0], g1[p][1], g1[p][2], g1[p][3], x, y);
            s += dir_eval(m2[p], g2[p][0], g2[p][1], g2[p][2], g2[p][3], x, y);
        }
    }

    // wave(64) shuffle reduce -> LDS -> one atomic per block
    #pragma unroll
    for (int o = 32; o > 0; o >>= 1) s += __shfl_down(s, o, 64);
    __shared__ float wsum[4];
    if (lane == 0) wsum[wv] = s;
    __syncthreads();
    if (threadIdx.x == 0) {
        float tsum = wsum[0] + wsum[1] + wsum[2] + wsum[3];
        atomicAdd(out, tsum * (1.0f / ((float)N * (float)H * (float)W)));
    }
}

extern "C" void kernel_launch(void* const* d_in, const int* in_sizes, int n_in,
                              void* d_out, int out_size, void* d_ws, size_t ws_size,
                              hipStream_t stream) {
    const float* A = (const float*)d_in[0];   // UV_AtoB [16,2,768,768]
    const float* B = (const float*)d_in[1];   // UV_BtoA [16,2,768,768]
    float* out = (float*)d_out;               // scalar fp32

    hipMemsetAsync(out, 0, sizeof(float), stream);

    dim3 grid(W / 64, H / (4 * PX), N);       // (12, 48, 16) = 9216 blocks
    cycle_loss_kernel<<<grid, 256, 0, stream>>>(A, B, out);
}